// Round 3
// baseline (183.941 us; speedup 1.0000x reference)
//
#include <hip/hip_runtime.h>
#include <math.h>

#define NB 8
#define NQ 256
#define NK 256
#define DIN 10
#define FDIM 64
#define HIDDEN 256
#define NH 8

#define FSTRIDE 72    // shorts per feat row (64 + 8 pad) -> 144 B
#define HSTRIDE 264   // shorts per h row (256 + 8 pad) -> 528 B

typedef float f32x4 __attribute__((ext_vector_type(4)));
typedef short bf16x8 __attribute__((ext_vector_type(8)));

// fast float->bf16: round-to-nearest, ties away (2 instrs)
__device__ __forceinline__ short f2bf(float f) {
    return (short)((__float_as_uint(f) + 0x8000u) >> 16);
}
// pack two floats -> two bf16 in one dword via v_perm (2 adds + 1 perm)
__device__ __forceinline__ unsigned pack2(float a, float b) {
    unsigned ua = __float_as_uint(a) + 0x8000u;   // low half
    unsigned ub = __float_as_uint(b) + 0x8000u;   // high half
    return __builtin_amdgcn_perm(ub, ua, 0x07060302);
}

__device__ __forceinline__ void four4(float x, float* dst) {
    float s1 = __sinf(x), c1 = __cosf(x);
    float s2 = 2.f * s1 * c1, c2 = 1.f - 2.f * s1 * s1;
    float s4 = 2.f * s2 * c2, c4 = 1.f - 2.f * s2 * s2;
    float s8 = 2.f * s4 * c4, c8 = 1.f - 2.f * s4 * s4;
    dst[0] = s1; dst[1] = s2; dst[2] = s4; dst[3] = s8;
    dst[4] = c1; dst[5] = c2; dst[6] = c4; dst[7] = c8;
}
__device__ __forceinline__ void four2(float x, float* dst) {
    float s1 = __sinf(x), c1 = __cosf(x);
    dst[0] = s1; dst[1] = 2.f * s1 * c1;
    dst[2] = c1; dst[3] = 1.f - 2.f * s1 * s1;
}

// Block = one (b,i): 256 pairs, 4 waves, 4 chunks of 64 pairs.
// MFMA 16x16x32 bf16: A[m=lane15][k=quad*8+e]; B[k=quad*8+e][n=lane15];
// D: row=quad*4+r, col=lane15.
// LDS 43008 B -> 3 blocks/CU (12 waves). W1+W2 fragments live in registers.
__global__ __launch_bounds__(256, 3) void relfeat_mfma_kernel(
    const float* __restrict__ q, const float* __restrict__ k,
    const float* __restrict__ W1, const float* __restrict__ b1,
    const float* __restrict__ W2, const float* __restrict__ b2,
    float* __restrict__ out)
{
    __shared__ __align__(16) short feat_c[64 * FSTRIDE];   //  9216 B (per-chunk)
    __shared__ __align__(16) short h_s[64 * HSTRIDE];      // 33792 B

    const int t = threadIdx.x;
    const int wave = t >> 6;
    const int lane15 = t & 15;
    const int quad = (t >> 4) & 3;
    const int b = blockIdx.x >> 8;
    const int i = blockIdx.x & (NQ - 1);

    // ---- per-thread k-row (this thread's pair j = t), wave-uniform q-row ----
    const float* kp = k + ((size_t)b * NK + t) * DIN;
    const float k0 = kp[0], k3 = kp[3], k4 = kp[4], k5 = kp[5], k6 = kp[6],
                k7 = kp[7], k8 = kp[8];
    const float* qp = q + ((size_t)b * NQ + i) * DIN;
    const float q0 = qp[0], q3 = qp[3], q4 = qp[4], q5 = qp[5], q6 = qp[6],
                q7 = qp[7], q8 = qp[8];

    // ---- W1 B-fragments (one-time, L2-hot): wave owns hidden slice n0..n0+63 ----
    const int n0 = wave * 64;
    bf16x8 bfrag[4][2];
#pragma unroll
    for (int nt = 0; nt < 4; ++nt)
#pragma unroll
        for (int ks = 0; ks < 2; ++ks) {
            const float* wp = W1 + (size_t)(ks * 32 + quad * 8) * HIDDEN
                              + (n0 + nt * 16 + lane15);
            bf16x8 v;
#pragma unroll
            for (int e = 0; e < 8; ++e) v[e] = f2bf(wp[(size_t)e * HIDDEN]);
            bfrag[nt][ks] = v;
        }
    float b1f[4];
#pragma unroll
    for (int nt = 0; nt < 4; ++nt) b1f[nt] = b1[n0 + nt * 16 + lane15];

    // ---- W2 B-fragments in registers (K=256 -> 8 steps; N=16, cols 8..15 zero) ----
    bf16x8 w2f[8];
#pragma unroll
    for (int ks = 0; ks < 8; ++ks) {
        bf16x8 v;
#pragma unroll
        for (int e = 0; e < 8; ++e)
            v[e] = (lane15 < NH) ? f2bf(W2[(size_t)(ks * 32 + quad * 8 + e) * NH + lane15])
                                 : (short)0;
        w2f[ks] = v;
    }
    const float b2v = (lane15 < NH) ? b2[lane15] : 0.f;

    // ---- main loop over 4 chunks of 64 pairs ----
#pragma unroll 1
    for (int m = 0; m < 4; ++m) {
        // Phase A: wave m computes + stages its 64 pairs' features
        if (wave == m) {
            const float dpx = k3 - q3, dpy = k4 - q4;
            const float dvx = k5 - q5, dvy = k6 - q6;
            const float dist = sqrtf(dpx * dpx + dpy * dpy + 1e-6f);
            const float inv_dist = 1.0f / (dist + 0.1f);
            const float inv_d2 = 1.0f / (dist + 1e-6f);
            const float bear_x = dpx * inv_d2, bear_y = dpy * inv_d2;
            const float ata = bear_x * q7 + bear_y * q8;
            const float aspect = bear_x * k7 + bear_y * k8;
            const float dot_dp_dv = dpx * dvx + dpy * dvy;
            const float speed_sq = dvx * dvx + dvy * dvy;
            const float ttca = tanhf(fmaxf(0.f, -dot_dp_dv / (speed_sq + 1e-6f)));
            const float same_team = (q0 == k0) ? 1.f : 0.f;
            const float q_speed = sqrtf(q5 * q5 + q6 * q6);
            const float k_speed = sqrtf(k5 * k5 + k6 * k6);
            const float delta_speed = k_speed - q_speed;

            float feat[FDIM];
            four4(dist,        feat + 0);
            four4(inv_dist,    feat + 8);
            four4(ata,         feat + 16);
            four4(aspect,      feat + 24);
            four2(dpx,         feat + 32);
            four2(dpy,         feat + 36);
            four2(dvx,         feat + 40);
            four2(dvy,         feat + 44);
            four2(ttca,        feat + 48);
            four2(dist,        feat + 52);
            four2(same_team,   feat + 56);
            four2(delta_speed, feat + 60);

            const int row = t & 63;  // pair within chunk
#pragma unroll
            for (int c8 = 0; c8 < 8; ++c8) {
                uint4 v;
                v.x = pack2(feat[c8 * 8 + 0], feat[c8 * 8 + 1]);
                v.y = pack2(feat[c8 * 8 + 2], feat[c8 * 8 + 3]);
                v.z = pack2(feat[c8 * 8 + 4], feat[c8 * 8 + 5]);
                v.w = pack2(feat[c8 * 8 + 6], feat[c8 * 8 + 7]);
                *(uint4*)&feat_c[row * FSTRIDE + c8 * 8] = v;
            }
        }
        __syncthreads();  // feat_c ready; h_s(m-1) GEMM2 reads complete

        // Phase B: GEMM1 (bias in C-init) -> silu -> h_s
        f32x4 acc[4][4];
#pragma unroll
        for (int mt = 0; mt < 4; ++mt)
#pragma unroll
            for (int nt = 0; nt < 4; ++nt) {
                const float bb = b1f[nt];
                acc[mt][nt] = (f32x4){bb, bb, bb, bb};
            }
#pragma unroll
        for (int ks = 0; ks < 2; ++ks)
#pragma unroll
            for (int mt = 0; mt < 4; ++mt) {
                const bf16x8 a = *(const bf16x8*)&feat_c[(mt * 16 + lane15) * FSTRIDE
                                                          + ks * 32 + quad * 8];
#pragma unroll
                for (int nt = 0; nt < 4; ++nt)
                    acc[mt][nt] = __builtin_amdgcn_mfma_f32_16x16x32_bf16(
                        a, bfrag[nt][ks], acc[mt][nt], 0, 0, 0);
            }

#pragma unroll
        for (int mt = 0; mt < 4; ++mt)
#pragma unroll
            for (int nt = 0; nt < 4; ++nt) {
                const int h = n0 + nt * 16 + lane15;
#pragma unroll
                for (int r = 0; r < 4; ++r) {
                    const int pair = mt * 16 + quad * 4 + r;
                    const float p = acc[mt][nt][r];
                    const float s = __fdividef(p, 1.f + __expf(-p));
                    h_s[pair * HSTRIDE + h] = f2bf(s);
                }
            }
        __syncthreads();  // h_s ready

        // Phase C: GEMM2 (wave owns 16 pairs, K=256), coalesced float4 stores
        const int pw = wave * 16;
        f32x4 acc2 = (f32x4){b2v, b2v, b2v, b2v};
#pragma unroll
        for (int ks = 0; ks < 8; ++ks) {
            const bf16x8 ha = *(const bf16x8*)&h_s[(pw + lane15) * HSTRIDE
                                                    + ks * 32 + quad * 8];
            acc2 = __builtin_amdgcn_mfma_f32_16x16x32_bf16(ha, w2f[ks], acc2, 0, 0, 0);
        }
        if (lane15 < NH) {
            float* op = out + (((size_t)b * NH + lane15) * NQ + i) * NK
                        + (m * 64 + pw + quad * 4);
            *(float4*)op = make_float4(acc2[0], acc2[1], acc2[2], acc2[3]);
        }
        // no end barrier needed: next chunk's Phase-A barrier orders
        // GEMM2 reads(m) before feat/h writes(m+1)
    }
}

extern "C" void kernel_launch(void* const* d_in, const int* in_sizes, int n_in,
                              void* d_out, int out_size, void* d_ws, size_t ws_size,
                              hipStream_t stream) {
    const float* q  = (const float*)d_in[0];
    const float* k  = (const float*)d_in[1];
    const float* W1 = (const float*)d_in[2];
    const float* b1 = (const float*)d_in[3];
    const float* W2 = (const float*)d_in[4];
    const float* b2 = (const float*)d_in[5];
    float* out = (float*)d_out;

    dim3 grid(NB * NQ);   // 2048 blocks: one per (b, i)
    dim3 block(NK);       // 256 threads = 4 waves
    relfeat_mfma_kernel<<<grid, block, 0, stream>>>(q, k, W1, b1, W2, b2, out);
}

// Round 4
// 147.138 us; speedup vs baseline: 1.2501x; 1.2501x over previous
//
#include <hip/hip_runtime.h>
#include <math.h>

#define NB 8
#define NQ 256
#define NK 256
#define DIN 10
#define FDIM 64
#define HIDDEN 256
#define NH 8

#define FSTRIDE 72    // shorts per feat row (64 + 8 pad) -> 144 B
#define HSTRIDE 264   // shorts per h row (256 + 8 pad) -> 528 B

typedef float f32x4 __attribute__((ext_vector_type(4)));
typedef short bf16x8 __attribute__((ext_vector_type(8)));

// fast float->bf16: round-to-nearest, ties away (2 instrs)
__device__ __forceinline__ short f2bf(float f) {
    return (short)((__float_as_uint(f) + 0x8000u) >> 16);
}
// pack two floats -> two bf16 in one dword (2 adds + 1 perm)
__device__ __forceinline__ unsigned pack2(float a, float b) {
    unsigned ua = __float_as_uint(a) + 0x8000u;   // -> low half
    unsigned ub = __float_as_uint(b) + 0x8000u;   // -> high half
    return __builtin_amdgcn_perm(ub, ua, 0x07060302);
}

__device__ __forceinline__ void four4(float x, float* dst) {
    float s1 = __sinf(x), c1 = __cosf(x);
    float s2 = 2.f * s1 * c1, c2 = 1.f - 2.f * s1 * s1;
    float s4 = 2.f * s2 * c2, c4 = 1.f - 2.f * s2 * s2;
    float s8 = 2.f * s4 * c4, c8 = 1.f - 2.f * s4 * s4;
    dst[0] = s1; dst[1] = s2; dst[2] = s4; dst[3] = s8;
    dst[4] = c1; dst[5] = c2; dst[6] = c4; dst[7] = c8;
}
__device__ __forceinline__ void four2(float x, float* dst) {
    float s1 = __sinf(x), c1 = __cosf(x);
    dst[0] = s1; dst[1] = 2.f * s1 * c1;
    dst[2] = c1; dst[3] = 1.f - 2.f * s1 * s1;
}

// Block = one (b,i): 256 pairs, 4 waves, 4 chunks of 64 pairs.
// Features: computed upfront by ALL threads (parallel), held packed-bf16 in
// 32 VGPRs/thread; wave m dumps its 64 rows into the 9.2 KB rotating feat_c
// at chunk m (divergent part = 8 ds_write_b128 only).
// MFMA 16x16x32 bf16: A[m=lane15][k=quad*8+e]; B[k=quad*8+e][n=lane15];
// D: row=quad*4+r, col=lane15.
// LDS 51456 B -> 3 blocks/CU. W1 frags in regs; W2 in LDS.
__global__ __launch_bounds__(256, 3) void relfeat_mfma_kernel(
    const float* __restrict__ q, const float* __restrict__ k,
    const float* __restrict__ W1, const float* __restrict__ b1,
    const float* __restrict__ W2, const float* __restrict__ b2,
    float* __restrict__ out)
{
    __shared__ __align__(16) short feat_c[64 * FSTRIDE];   //  9216 B (rotating)
    __shared__ __align__(16) short h_s[64 * HSTRIDE];      // 33792 B
    __shared__ __align__(16) short w2_s[16 * HSTRIDE];     //  8448 B

    const int t = threadIdx.x;
    const int wave = t >> 6;
    const int lane15 = t & 15;
    const int quad = (t >> 4) & 3;
    const int b = blockIdx.x >> 8;
    const int i = blockIdx.x & (NQ - 1);

    // ---- features for this thread's pair j = t (all threads in parallel) ----
    uint4 fpack[8];   // 64 bf16 = 32 dwords
    {
        const float* kp = k + ((size_t)b * NK + t) * DIN;
        const float k0 = kp[0], k3 = kp[3], k4 = kp[4], k5 = kp[5], k6 = kp[6],
                    k7 = kp[7], k8 = kp[8];
        const float* qp = q + ((size_t)b * NQ + i) * DIN;
        const float q0 = qp[0], q3 = qp[3], q4 = qp[4], q5 = qp[5], q6 = qp[6],
                    q7 = qp[7], q8 = qp[8];

        const float dpx = k3 - q3, dpy = k4 - q4;
        const float dvx = k5 - q5, dvy = k6 - q6;
        const float dist = sqrtf(dpx * dpx + dpy * dpy + 1e-6f);
        const float inv_dist = 1.0f / (dist + 0.1f);
        const float inv_d2 = 1.0f / (dist + 1e-6f);
        const float bear_x = dpx * inv_d2, bear_y = dpy * inv_d2;
        const float ata = bear_x * q7 + bear_y * q8;
        const float aspect = bear_x * k7 + bear_y * k8;
        const float dot_dp_dv = dpx * dvx + dpy * dvy;
        const float speed_sq = dvx * dvx + dvy * dvy;
        const float ttca = tanhf(fmaxf(0.f, -dot_dp_dv / (speed_sq + 1e-6f)));
        const float same_team = (q0 == k0) ? 1.f : 0.f;
        const float q_speed = sqrtf(q5 * q5 + q6 * q6);
        const float k_speed = sqrtf(k5 * k5 + k6 * k6);
        const float delta_speed = k_speed - q_speed;

        float feat[FDIM];
        four4(dist,        feat + 0);
        four4(inv_dist,    feat + 8);
        four4(ata,         feat + 16);
        four4(aspect,      feat + 24);
        four2(dpx,         feat + 32);
        four2(dpy,         feat + 36);
        four2(dvx,         feat + 40);
        four2(dvy,         feat + 44);
        four2(ttca,        feat + 48);
        four2(dist,        feat + 52);
        four2(same_team,   feat + 56);
        four2(delta_speed, feat + 60);

#pragma unroll
        for (int c8 = 0; c8 < 8; ++c8) {
            fpack[c8].x = pack2(feat[c8 * 8 + 0], feat[c8 * 8 + 1]);
            fpack[c8].y = pack2(feat[c8 * 8 + 2], feat[c8 * 8 + 3]);
            fpack[c8].z = pack2(feat[c8 * 8 + 4], feat[c8 * 8 + 5]);
            fpack[c8].w = pack2(feat[c8 * 8 + 6], feat[c8 * 8 + 7]);
        }
    }

    // ---- stage W2^T (o-major) into LDS; zero pad rows 8..15 ----
    for (int idx = t; idx < 8 * HSTRIDE; idx += 256) w2_s[8 * HSTRIDE + idx] = 0;
#pragma unroll
    for (int o = 0; o < NH; ++o) w2_s[o * HSTRIDE + t] = f2bf(W2[t * NH + o]);

    // ---- W1 B-fragments (one-time, L2-hot): wave owns hidden slice n0..n0+63 ----
    const int n0 = wave * 64;
    bf16x8 bfrag[4][2];
#pragma unroll
    for (int nt = 0; nt < 4; ++nt)
#pragma unroll
        for (int ks = 0; ks < 2; ++ks) {
            const float* wp = W1 + (size_t)(ks * 32 + quad * 8) * HIDDEN
                              + (n0 + nt * 16 + lane15);
            bf16x8 v;
#pragma unroll
            for (int e = 0; e < 8; ++e) v[e] = f2bf(wp[(size_t)e * HIDDEN]);
            bfrag[nt][ks] = v;
        }
    float b1f[4];
#pragma unroll
    for (int nt = 0; nt < 4; ++nt) b1f[nt] = b1[n0 + nt * 16 + lane15];
    const float b2v = (lane15 < NH) ? b2[lane15] : 0.f;

    // ---- main loop over 4 chunks of 64 pairs ----
#pragma unroll 1
    for (int m = 0; m < 4; ++m) {
        // Phase A: wave m dumps its pre-computed packed features (8 b128 stores)
        if (wave == m) {
            const int row = t & 63;
#pragma unroll
            for (int c8 = 0; c8 < 8; ++c8)
                *(uint4*)&feat_c[row * FSTRIDE + c8 * 8] = fpack[c8];
        }
        __syncthreads();  // feat_c(m) ready; also fences h_s(m-1) GEMM2 reads

        // Phase B: GEMM1 (bias in C-init) -> silu -> h_s
        f32x4 acc[4][4];
#pragma unroll
        for (int mt = 0; mt < 4; ++mt)
#pragma unroll
            for (int nt = 0; nt < 4; ++nt) {
                const float bb = b1f[nt];
                acc[mt][nt] = (f32x4){bb, bb, bb, bb};
            }
#pragma unroll
        for (int ks = 0; ks < 2; ++ks)
#pragma unroll
            for (int mt = 0; mt < 4; ++mt) {
                const bf16x8 a = *(const bf16x8*)&feat_c[(mt * 16 + lane15) * FSTRIDE
                                                          + ks * 32 + quad * 8];
#pragma unroll
                for (int nt = 0; nt < 4; ++nt)
                    acc[mt][nt] = __builtin_amdgcn_mfma_f32_16x16x32_bf16(
                        a, bfrag[nt][ks], acc[mt][nt], 0, 0, 0);
            }

#pragma unroll
        for (int mt = 0; mt < 4; ++mt)
#pragma unroll
            for (int nt = 0; nt < 4; ++nt) {
                const int h = n0 + nt * 16 + lane15;
#pragma unroll
                for (int r = 0; r < 4; ++r) {
                    const int pair = mt * 16 + quad * 4 + r;
                    const float p = acc[mt][nt][r];
                    const float s = p * __frcp_rn(1.f + __expf(-p));  // silu
                    h_s[pair * HSTRIDE + h] = f2bf(s);
                }
            }
        __syncthreads();  // h_s(m) ready

        // Phase C: GEMM2 (wave owns 16 pairs, K=256), coalesced float4 stores
        const int pw = wave * 16;
        f32x4 acc2 = (f32x4){b2v, b2v, b2v, b2v};
#pragma unroll
        for (int ks = 0; ks < 8; ++ks) {
            const bf16x8 ha = *(const bf16x8*)&h_s[(pw + lane15) * HSTRIDE
                                                    + ks * 32 + quad * 8];
            const bf16x8 wb = *(const bf16x8*)&w2_s[lane15 * HSTRIDE
                                                     + ks * 32 + quad * 8];
            acc2 = __builtin_amdgcn_mfma_f32_16x16x32_bf16(ha, wb, acc2, 0, 0, 0);
        }
        if (lane15 < NH) {
            float* op = out + (((size_t)b * NH + lane15) * NQ + i) * NK
                        + (m * 64 + pw + quad * 4);
            *(float4*)op = make_float4(acc2[0], acc2[1], acc2[2], acc2[3]);
        }
        // next chunk's Phase-A barrier orders GEMM2(m) reads before writes(m+1)
    }
}

extern "C" void kernel_launch(void* const* d_in, const int* in_sizes, int n_in,
                              void* d_out, int out_size, void* d_ws, size_t ws_size,
                              hipStream_t stream) {
    const float* q  = (const float*)d_in[0];
    const float* k  = (const float*)d_in[1];
    const float* W1 = (const float*)d_in[2];
    const float* b1 = (const float*)d_in[3];
    const float* W2 = (const float*)d_in[4];
    const float* b2 = (const float*)d_in[5];
    float* out = (float*)d_out;

    dim3 grid(NB * NQ);   // 2048 blocks: one per (b, i)
    dim3 block(NK);       // 256 threads = 4 waves
    relfeat_mfma_kernel<<<grid, block, 0, stream>>>(q, k, W1, b1, W2, b2, out);
}

// Round 5
// 120.240 us; speedup vs baseline: 1.5298x; 1.2237x over previous
//
#include <hip/hip_runtime.h>
#include <math.h>

#define NB 8
#define NQ 256
#define NK 256
#define DIN 10
#define FDIM 64
#define HIDDEN 256
#define NH 8

#define FSTRIDE 72    // shorts per feat row (64 + 8 pad) -> 144 B, 16B-aligned
#define HSTRIDE 264   // shorts per h row (256 + 8 pad) -> 528 B, 16B-aligned

typedef float f32x4 __attribute__((ext_vector_type(4)));
typedef short bf16x8 __attribute__((ext_vector_type(8)));

// fast float->bf16: round-to-nearest, ties away (2 instrs)
__device__ __forceinline__ short f2bf(float f) {
    return (short)((__float_as_uint(f) + 0x8000u) >> 16);
}
// pack two floats -> two bf16 in one dword (2 adds + 1 perm)
__device__ __forceinline__ unsigned pack2(float a, float b) {
    unsigned ua = __float_as_uint(a) + 0x8000u;   // -> low half
    unsigned ub = __float_as_uint(b) + 0x8000u;   // -> high half
    return __builtin_amdgcn_perm(ub, ua, 0x07060302);
}

__device__ __forceinline__ void four4(float x, float* dst) {
    float s1 = __sinf(x), c1 = __cosf(x);
    float s2 = 2.f * s1 * c1, c2 = 1.f - 2.f * s1 * s1;
    float s4 = 2.f * s2 * c2, c4 = 1.f - 2.f * s2 * s2;
    float s8 = 2.f * s4 * c4, c8 = 1.f - 2.f * s4 * s4;
    dst[0] = s1; dst[1] = s2; dst[2] = s4; dst[3] = s8;
    dst[4] = c1; dst[5] = c2; dst[6] = c4; dst[7] = c8;
}
__device__ __forceinline__ void four2(float x, float* dst) {
    float s1 = __sinf(x), c1 = __cosf(x);
    dst[0] = s1; dst[1] = 2.f * s1 * c1;
    dst[2] = c1; dst[3] = 1.f - 2.f * s1 * s1;
}

// Block = one (b,i): 256 pairs, 4 waves, 4 chunks of 64 pairs.
// Features: all threads compute in parallel, write IMMEDIATELY to full feat_s
// (no long-lived registers -> no spill; lesson from r3/r4).
// MFMA 16x16x32 bf16: A[m=lane15][k=quad*8+e]; B[k=quad*8+e][n=lane15];
// D: row=quad*4+r, col=lane15.
// LDS 79104 B -> 2 blocks/CU. W1 frags in regs; W2 in LDS.
__global__ __launch_bounds__(256, 2) void relfeat_mfma_kernel(
    const float* __restrict__ q, const float* __restrict__ k,
    const float* __restrict__ W1, const float* __restrict__ b1,
    const float* __restrict__ W2, const float* __restrict__ b2,
    float* __restrict__ out)
{
    __shared__ __align__(16) short feat_s[NK * FSTRIDE];   // 36864 B
    __shared__ __align__(16) short h_s[64 * HSTRIDE];      // 33792 B
    __shared__ __align__(16) short w2_s[16 * HSTRIDE];     //  8448 B

    const int t = threadIdx.x;
    const int wave = t >> 6;
    const int lane15 = t & 15;
    const int quad = (t >> 4) & 3;
    const int b = blockIdx.x >> 8;
    const int i = blockIdx.x & (NQ - 1);

    // ---- features for pair j = t: compute and write to LDS immediately ----
    {
        const float* kp = k + ((size_t)b * NK + t) * DIN;
        const float k0 = kp[0], k3 = kp[3], k4 = kp[4], k5 = kp[5], k6 = kp[6],
                    k7 = kp[7], k8 = kp[8];
        const float* qp = q + ((size_t)b * NQ + i) * DIN;
        const float q0 = qp[0], q3 = qp[3], q4 = qp[4], q5 = qp[5], q6 = qp[6],
                    q7 = qp[7], q8 = qp[8];

        const float dpx = k3 - q3, dpy = k4 - q4;
        const float dvx = k5 - q5, dvy = k6 - q6;
        const float dist = sqrtf(dpx * dpx + dpy * dpy + 1e-6f);
        const float inv_dist = 1.0f / (dist + 0.1f);
        const float inv_d2 = 1.0f / (dist + 1e-6f);
        const float bear_x = dpx * inv_d2, bear_y = dpy * inv_d2;
        const float ata = bear_x * q7 + bear_y * q8;
        const float aspect = bear_x * k7 + bear_y * k8;
        const float dot_dp_dv = dpx * dvx + dpy * dvy;
        const float speed_sq = dvx * dvx + dvy * dvy;
        const float ttca = tanhf(fmaxf(0.f, -dot_dp_dv / (speed_sq + 1e-6f)));
        const float same_team = (q0 == k0) ? 1.f : 0.f;
        const float q_speed = sqrtf(q5 * q5 + q6 * q6);
        const float k_speed = sqrtf(k5 * k5 + k6 * k6);
        const float delta_speed = k_speed - q_speed;

        float feat[FDIM];
        four4(dist,        feat + 0);
        four4(inv_dist,    feat + 8);
        four4(ata,         feat + 16);
        four4(aspect,      feat + 24);
        four2(dpx,         feat + 32);
        four2(dpy,         feat + 36);
        four2(dvx,         feat + 40);
        four2(dvy,         feat + 44);
        four2(ttca,        feat + 48);
        four2(dist,        feat + 52);
        four2(same_team,   feat + 56);
        four2(delta_speed, feat + 60);

#pragma unroll
        for (int c8 = 0; c8 < 8; ++c8) {
            uint4 v;
            v.x = pack2(feat[c8 * 8 + 0], feat[c8 * 8 + 1]);
            v.y = pack2(feat[c8 * 8 + 2], feat[c8 * 8 + 3]);
            v.z = pack2(feat[c8 * 8 + 4], feat[c8 * 8 + 5]);
            v.w = pack2(feat[c8 * 8 + 6], feat[c8 * 8 + 7]);
            *(uint4*)&feat_s[t * FSTRIDE + c8 * 8] = v;   // immediate store
        }
    }

    // ---- stage W2^T (o-major) into LDS; zero pad rows 8..15 ----
    for (int idx = t; idx < 8 * HSTRIDE; idx += 256) w2_s[8 * HSTRIDE + idx] = 0;
#pragma unroll
    for (int o = 0; o < NH; ++o) w2_s[o * HSTRIDE + t] = f2bf(W2[t * NH + o]);

    // ---- W1 B-fragments (one-time, L2-hot): wave owns hidden slice n0..n0+63 ----
    const int n0 = wave * 64;
    bf16x8 bfrag[4][2];
#pragma unroll
    for (int nt = 0; nt < 4; ++nt)
#pragma unroll
        for (int ks = 0; ks < 2; ++ks) {
            const float* wp = W1 + (size_t)(ks * 32 + quad * 8) * HIDDEN
                              + (n0 + nt * 16 + lane15);
            bf16x8 v;
#pragma unroll
            for (int e = 0; e < 8; ++e) v[e] = f2bf(wp[(size_t)e * HIDDEN]);
            bfrag[nt][ks] = v;
        }
    float b1f[4];
#pragma unroll
    for (int nt = 0; nt < 4; ++nt) b1f[nt] = b1[n0 + nt * 16 + lane15];
    const float b2v = (lane15 < NH) ? b2[lane15] : 0.f;

    __syncthreads();  // feat_s + w2_s ready

    // ---- main loop over 4 chunks of 64 pairs ----
#pragma unroll 1
    for (int m = 0; m < 4; ++m) {
        const int p0 = m * 64;

        // GEMM1 (bias in C-init) over this chunk
        f32x4 acc[4][4];
#pragma unroll
        for (int mt = 0; mt < 4; ++mt)
#pragma unroll
            for (int nt = 0; nt < 4; ++nt) {
                const float bb = b1f[nt];
                acc[mt][nt] = (f32x4){bb, bb, bb, bb};
            }
#pragma unroll
        for (int ks = 0; ks < 2; ++ks)
#pragma unroll
            for (int mt = 0; mt < 4; ++mt) {
                const bf16x8 a = *(const bf16x8*)&feat_s[(p0 + mt * 16 + lane15) * FSTRIDE
                                                          + ks * 32 + quad * 8];
#pragma unroll
                for (int nt = 0; nt < 4; ++nt)
                    acc[mt][nt] = __builtin_amdgcn_mfma_f32_16x16x32_bf16(
                        a, bfrag[nt][ks], acc[mt][nt], 0, 0, 0);
            }

        // silu (cheap: exp2 + raw v_rcp) -> bf16 -> h_s
#pragma unroll
        for (int mt = 0; mt < 4; ++mt)
#pragma unroll
            for (int nt = 0; nt < 4; ++nt) {
                const int h = n0 + nt * 16 + lane15;
#pragma unroll
                for (int r = 0; r < 4; ++r) {
                    const int pair = mt * 16 + quad * 4 + r;
                    const float p = acc[mt][nt][r];
                    const float e = __builtin_amdgcn_exp2f(p * -1.44269504f);
                    const float s = p * __builtin_amdgcn_rcpf(1.f + e);
                    h_s[pair * HSTRIDE + h] = f2bf(s);
                }
            }
        __syncthreads();  // h_s(m) ready

        // GEMM2 (wave owns 16 pairs, K=256), coalesced float4 stores
        const int pw = wave * 16;
        f32x4 acc2 = (f32x4){b2v, b2v, b2v, b2v};
#pragma unroll
        for (int ks = 0; ks < 8; ++ks) {
            const bf16x8 ha = *(const bf16x8*)&h_s[(pw + lane15) * HSTRIDE
                                                    + ks * 32 + quad * 8];
            const bf16x8 wb = *(const bf16x8*)&w2_s[lane15 * HSTRIDE
                                                     + ks * 32 + quad * 8];
            acc2 = __builtin_amdgcn_mfma_f32_16x16x32_bf16(ha, wb, acc2, 0, 0, 0);
        }
        if (lane15 < NH) {
            float* op = out + (((size_t)b * NH + lane15) * NQ + i) * NK
                        + (p0 + pw + quad * 4);
            *(float4*)op = make_float4(acc2[0], acc2[1], acc2[2], acc2[3]);
        }
        __syncthreads();  // protect h_s before next chunk overwrites
    }
}

extern "C" void kernel_launch(void* const* d_in, const int* in_sizes, int n_in,
                              void* d_out, int out_size, void* d_ws, size_t ws_size,
                              hipStream_t stream) {
    const float* q  = (const float*)d_in[0];
    const float* k  = (const float*)d_in[1];
    const float* W1 = (const float*)d_in[2];
    const float* b1 = (const float*)d_in[3];
    const float* W2 = (const float*)d_in[4];
    const float* b2 = (const float*)d_in[5];
    float* out = (float*)d_out;

    dim3 grid(NB * NQ);   // 2048 blocks: one per (b, i)
    dim3 block(NK);       // 256 threads = 4 waves
    relfeat_mfma_kernel<<<grid, block, 0, stream>>>(q, k, W1, b1, W2, b2, out);
}

// Round 7
// 117.821 us; speedup vs baseline: 1.5612x; 1.0205x over previous
//
#include <hip/hip_runtime.h>
#include <math.h>

#define NB 8
#define NQ 256
#define NK 256
#define DIN 10
#define FDIM 64
#define HIDDEN 256
#define NH 8

#define FSTRIDE 64    // shorts per feat row; XOR-swizzled 8-short col-blocks, no pad
#define HSTRIDE 264   // shorts per h row (256 + 8 pad) -> 528 B
#define W2S 256       // shorts per w2 row (8 rows, no pad)

typedef float f32x4 __attribute__((ext_vector_type(4)));
typedef short bf16x8 __attribute__((ext_vector_type(8)));

// fast float->bf16: round-to-nearest, ties away (2 instrs)
__device__ __forceinline__ short f2bf(float f) {
    return (short)((__float_as_uint(f) + 0x8000u) >> 16);
}
// pack two floats -> two bf16 in one dword (2 adds + 1 perm)
__device__ __forceinline__ unsigned pack2(float a, float b) {
    unsigned ua = __float_as_uint(a) + 0x8000u;   // -> low half
    unsigned ub = __float_as_uint(b) + 0x8000u;   // -> high half
    return __builtin_amdgcn_perm(ub, ua, 0x07060302);
}

__device__ __forceinline__ void four4(float x, float* dst) {
    float s1 = __sinf(x), c1 = __cosf(x);
    float s2 = 2.f * s1 * c1, c2 = 1.f - 2.f * s1 * s1;
    float s4 = 2.f * s2 * c2, c4 = 1.f - 2.f * s2 * s2;
    float s8 = 2.f * s4 * c4, c8 = 1.f - 2.f * s4 * s4;
    dst[0] = s1; dst[1] = s2; dst[2] = s4; dst[3] = s8;
    dst[4] = c1; dst[5] = c2; dst[6] = c4; dst[7] = c8;
}
__device__ __forceinline__ void four2(float x, float* dst) {
    float s1 = __sinf(x), c1 = __cosf(x);
    dst[0] = s1; dst[1] = 2.f * s1 * c1;
    dst[2] = c1; dst[3] = 1.f - 2.f * s1 * s1;
}

// Block = one (b,i): 256 pairs, 4 waves, 8 half-chunks of 32 pairs.
// Feature phase: r5's proven pair-parallel upfront computation (exact math),
// immediate store to feat_s with XOR col-block swizzle (block^(row&7)) so
// FSTRIDE=64 needs no padding (reads: 8 bank-quads x 2-way = free).
// MFMA 16x16x32 bf16: A[m=lane15][k=quad*8+e]; B[k=quad*8+e][n=lane15];
// D: row=quad*4+r, col=lane15.
// GEMM2 per half-chunk runs on waves 0,1 only (one 16-pair M-tile each);
// w2_s has 8 rows, lanes 8..15 read duplicates (outputs unused, not stored).
// LDS 53760 B -> 3 blocks/CU.
__global__ __launch_bounds__(256, 3) void relfeat_mfma_kernel(
    const float* __restrict__ q, const float* __restrict__ k,
    const float* __restrict__ W1, const float* __restrict__ b1,
    const float* __restrict__ W2, const float* __restrict__ b2,
    float* __restrict__ out)
{
    __shared__ __align__(16) short feat_s[NK * FSTRIDE];   // 32768 B
    __shared__ __align__(16) short h_s[32 * HSTRIDE];      // 16896 B
    __shared__ __align__(16) short w2_s[8 * W2S];          //  4096 B

    const int t = threadIdx.x;
    const int wave = t >> 6;
    const int lane15 = t & 15;
    const int quad = (t >> 4) & 3;
    const int b = blockIdx.x >> 8;
    const int i = blockIdx.x & (NQ - 1);

    // ---- features for pair j = t (r5 verbatim), swizzled immediate store ----
    {
        const float* kp = k + ((size_t)b * NK + t) * DIN;
        const float k0 = kp[0], k3 = kp[3], k4 = kp[4], k5 = kp[5], k6 = kp[6],
                    k7 = kp[7], k8 = kp[8];
        const float* qp = q + ((size_t)b * NQ + i) * DIN;
        const float q0 = qp[0], q3 = qp[3], q4 = qp[4], q5 = qp[5], q6 = qp[6],
                    q7 = qp[7], q8 = qp[8];

        const float dpx = k3 - q3, dpy = k4 - q4;
        const float dvx = k5 - q5, dvy = k6 - q6;
        const float dist = sqrtf(dpx * dpx + dpy * dpy + 1e-6f);
        const float inv_dist = 1.0f / (dist + 0.1f);
        const float inv_d2 = 1.0f / (dist + 1e-6f);
        const float bear_x = dpx * inv_d2, bear_y = dpy * inv_d2;
        const float ata = bear_x * q7 + bear_y * q8;
        const float aspect = bear_x * k7 + bear_y * k8;
        const float dot_dp_dv = dpx * dvx + dpy * dvy;
        const float speed_sq = dvx * dvx + dvy * dvy;
        const float ttca = tanhf(fmaxf(0.f, -dot_dp_dv / (speed_sq + 1e-6f)));
        const float same_team = (q0 == k0) ? 1.f : 0.f;
        const float q_speed = sqrtf(q5 * q5 + q6 * q6);
        const float k_speed = sqrtf(k5 * k5 + k6 * k6);
        const float delta_speed = k_speed - q_speed;

        float feat[FDIM];
        four4(dist,        feat + 0);
        four4(inv_dist,    feat + 8);
        four4(ata,         feat + 16);
        four4(aspect,      feat + 24);
        four2(dpx,         feat + 32);
        four2(dpy,         feat + 36);
        four2(dvx,         feat + 40);
        four2(dvy,         feat + 44);
        four2(ttca,        feat + 48);
        four2(dist,        feat + 52);
        four2(same_team,   feat + 56);
        four2(delta_speed, feat + 60);

        const int sw = t & 7;  // row-dependent XOR swizzle of 8-short blocks
#pragma unroll
        for (int c8 = 0; c8 < 8; ++c8) {
            uint4 v;
            v.x = pack2(feat[c8 * 8 + 0], feat[c8 * 8 + 1]);
            v.y = pack2(feat[c8 * 8 + 2], feat[c8 * 8 + 3]);
            v.z = pack2(feat[c8 * 8 + 4], feat[c8 * 8 + 5]);
            v.w = pack2(feat[c8 * 8 + 6], feat[c8 * 8 + 7]);
            *(uint4*)&feat_s[t * FSTRIDE + ((c8 ^ sw) * 8)] = v;
        }
    }

    // ---- stage W2^T (o-major, 8 rows, no pad): w2_s[o][k] = W2[k][o] ----
#pragma unroll
    for (int o = 0; o < NH; ++o) w2_s[o * W2S + t] = f2bf(W2[t * NH + o]);

    // ---- W1 B-fragments (one-time, L2-hot): wave owns hidden slice n0..n0+63 ----
    const int n0 = wave * 64;
    bf16x8 bfrag[4][2];
#pragma unroll
    for (int nt = 0; nt < 4; ++nt)
#pragma unroll
        for (int ks = 0; ks < 2; ++ks) {
            const float* wp = W1 + (size_t)(ks * 32 + quad * 8) * HIDDEN
                              + (n0 + nt * 16 + lane15);
            bf16x8 v;
#pragma unroll
            for (int e = 0; e < 8; ++e) v[e] = f2bf(wp[(size_t)e * HIDDEN]);
            bfrag[nt][ks] = v;
        }
    float b1f[4];
#pragma unroll
    for (int nt = 0; nt < 4; ++nt) b1f[nt] = b1[n0 + nt * 16 + lane15];
    const float b2v = (lane15 < NH) ? b2[lane15] : 0.f;

    __syncthreads();  // feat_s + w2_s ready

    // ---- main loop: 8 half-chunks of 32 pairs ----
    const int swr = lane15 & 7;  // row&7 for A-frag reads (rows = p0h+mt*16+lane15)
#pragma unroll 1
    for (int hc = 0; hc < 8; ++hc) {
        const int p0h = hc * 32;

        // GEMM1 (bias in C-init) over 32 pairs x this wave's 64 hidden
        f32x4 acc[2][4];
#pragma unroll
        for (int mt = 0; mt < 2; ++mt)
#pragma unroll
            for (int nt = 0; nt < 4; ++nt) {
                const float bb = b1f[nt];
                acc[mt][nt] = (f32x4){bb, bb, bb, bb};
            }
#pragma unroll
        for (int ks = 0; ks < 2; ++ks)
#pragma unroll
            for (int mt = 0; mt < 2; ++mt) {
                const int row = p0h + mt * 16 + lane15;
                const bf16x8 a = *(const bf16x8*)
                    &feat_s[row * FSTRIDE + (((ks * 4 + quad) ^ swr) * 8)];
#pragma unroll
                for (int nt = 0; nt < 4; ++nt)
                    acc[mt][nt] = __builtin_amdgcn_mfma_f32_16x16x32_bf16(
                        a, bfrag[nt][ks], acc[mt][nt], 0, 0, 0);
            }

        // silu (r5-proven exp2 + v_rcp) -> bf16 -> h_s (rows 0..31)
#pragma unroll
        for (int mt = 0; mt < 2; ++mt)
#pragma unroll
            for (int nt = 0; nt < 4; ++nt) {
                const int h = n0 + nt * 16 + lane15;
#pragma unroll
                for (int r = 0; r < 4; ++r) {
                    const int pair = mt * 16 + quad * 4 + r;
                    const float pv = acc[mt][nt][r];
                    const float e = __builtin_amdgcn_exp2f(pv * -1.44269504f);
                    const float s = pv * __builtin_amdgcn_rcpf(1.f + e);
                    h_s[pair * HSTRIDE + h] = f2bf(s);
                }
            }
        __syncthreads();  // h_s(hc) ready

        // GEMM2: waves 0,1 each take one 16-pair M-tile; K=256
        if (wave < 2) {
            const int pw = wave * 16;
            f32x4 acc2 = (f32x4){b2v, b2v, b2v, b2v};
#pragma unroll
            for (int ks = 0; ks < 8; ++ks) {
                const bf16x8 ha = *(const bf16x8*)&h_s[(pw + lane15) * HSTRIDE
                                                        + ks * 32 + quad * 8];
                const bf16x8 wb = *(const bf16x8*)&w2_s[(lane15 & 7) * W2S
                                                         + ks * 32 + quad * 8];
                acc2 = __builtin_amdgcn_mfma_f32_16x16x32_bf16(ha, wb, acc2, 0, 0, 0);
            }
            if (lane15 < NH) {
                float* op = out + (((size_t)b * NH + lane15) * NQ + i) * NK
                            + (p0h + pw + quad * 4);
                *(float4*)op = make_float4(acc2[0], acc2[1], acc2[2], acc2[3]);
            }
        }
        __syncthreads();  // h_s consumed before next half-chunk overwrites
    }
}

extern "C" void kernel_launch(void* const* d_in, const int* in_sizes, int n_in,
                              void* d_out, int out_size, void* d_ws, size_t ws_size,
                              hipStream_t stream) {
    const float* q  = (const float*)d_in[0];
    const float* k  = (const float*)d_in[1];
    const float* W1 = (const float*)d_in[2];
    const float* b1 = (const float*)d_in[3];
    const float* W2 = (const float*)d_in[4];
    const float* b2 = (const float*)d_in[5];
    float* out = (float*)d_out;

    dim3 grid(NB * NQ);   // 2048 blocks: one per (b, i)
    dim3 block(NK);       // 256 threads = 4 waves
    relfeat_mfma_kernel<<<grid, block, 0, stream>>>(q, k, W1, b1, W2, b2, out);
}